// Round 16
// baseline (664.637 us; speedup 1.0000x reference)
//
#include <hip/hip_runtime.h>
#include <stdint.h>

// PointerNet: B=8, F=4000, S=512, E=H=128, TOPK=8, USE_MASK=1, EPS=1e-4
#define S_    512
#define B_    8
#define F_    4000
#define E_    128
#define H_    128
#define TOPK_ 8
#define S2_   (S_*S_)        // 262144
#define BSS_  (B_*S2_)       // 2097152
#define BSE_  (B_*S_*E_)     // 524288 (f64 elements per embed partial = 4MB)
#define NCHUNK_ 8
typedef unsigned long long ull;
typedef __attribute__((ext_vector_type(4))) double d4;

// ---------------- threefry2x32 (exact JAX semantics) ----------------
__device__ __forceinline__ void tf2x32(uint32_t k0, uint32_t k1, uint32_t& x0, uint32_t& x1) {
  uint32_t k2 = k0 ^ k1 ^ 0x1BD11BDAu;
  x0 += k0; x1 += k1;
#define TFR(r) { x0 += x1; x1 = (x1 << (r)) | (x1 >> (32 - (r))); x1 ^= x0; }
  TFR(13) TFR(15) TFR(26) TFR(6)
  x0 += k1; x1 += k2 + 1u;
  TFR(17) TFR(29) TFR(16) TFR(24)
  x0 += k2; x1 += k0 + 2u;
  TFR(13) TFR(15) TFR(26) TFR(6)
  x0 += k0; x1 += k1 + 3u;
  TFR(17) TFR(29) TFR(16) TFR(24)
  x0 += k1; x1 += k2 + 4u;
  TFR(13) TFR(15) TFR(26) TFR(6)
  x0 += k2; x1 += k0 + 5u;
#undef TFR
}

// jax_threefry_partitionable=True (modern JAX default)
__device__ __forceinline__ void splitkey(int i, uint32_t& k0, uint32_t& k1) {
  uint32_t x0 = 0u, x1 = (uint32_t)i;
  tf2x32(0u, 42u, x0, x1);   // key(42) = (0, 42)
  k0 = x0; k1 = x1;
}
__device__ __forceinline__ uint32_t randbits32(uint32_t k0, uint32_t k1, uint32_t m) {
  uint32_t x0 = 0u, x1 = m;
  tf2x32(k0, k1, x0, x1);
  return x0 ^ x1;
}

// ---------------- stage A: split-K partial f64 GEMM via f64 MFMA, self-calibrating ----------------
// Wave computes a 16(s) x 16(e) tile of part[c][b] over K = F-chunk, 4 k per MFMA.
// Fragment lane-mapping PROBED at runtime (2 MFMAs); unknown signature -> VALU fallback.
__global__ __launch_bounds__(256) void embed_kernel(const float* __restrict__ inputs,
                                                    const float* __restrict__ embedding,
                                                    double* __restrict__ part) {
  const int wid = blockIdx.x*4 + (threadIdx.x >> 6);
  const int c  = wid >> 11;                  // F-chunk 0..7
  const int b  = (wid >> 8) & 7;
  const int s0 = ((wid >> 3) & 31) << 4;
  const int e0 = (wid & 7) << 4;
  const int fbeg = c << 9;
  const int fend = (fbeg + 512 < F_) ? fbeg + 512 : F_;   // 512,...,512,416 (all %4==0)
  const int l  = threadIdx.x & 63;

  // ---- probe the HW fragment mapping (wave-uniform signatures) ----
  d4 z = {0.0, 0.0, 0.0, 0.0};
  double lv = (double)l;
  d4 p1 = __builtin_amdgcn_mfma_f64_16x16x4f64(lv, 1.0, z, 0, 0, 0);  // D[m][n]=sum_k A[m][k]
  d4 p2 = __builtin_amdgcn_mfma_f64_16x16x4f64(1.0, lv, z, 0, 0, 0);  // D[m][n]=sum_k B[k][n]
  const int sig1 = __builtin_amdgcn_readlane((int)p1[1], 0);  // 100/112/22/70 -> (A,D) combo
  const int sig2 = __builtin_amdgcn_readlane((int)p2[0], 1);  // 100/22       -> B combo
  const bool known = (sig1 == 100 || sig1 == 112 || sig1 == 22 || sig1 == 70) &&
                     (sig2 == 100 || sig2 == 22);

  if (known) {
    const bool A2 = (sig1 == 22) || (sig1 == 70);
    const bool D2 = (sig1 == 112) || (sig1 == 70);
    const bool B2 = (sig2 == 22);
    const int mA = A2 ? (l >> 2) : (l & 15);
    const int kA = A2 ? (l & 3)  : (l >> 4);
    const int nB = B2 ? (l >> 2) : (l & 15);
    const int kB = B2 ? (l & 3)  : (l >> 4);
    const float* Ap = inputs    + (size_t)(b*F_ + fbeg + kA)*S_ + s0 + mA;  // A[m][k]=in[f][s]
    const float* Bp = embedding + (size_t)(fbeg + kB)*E_ + e0 + nB;         // B[k][n]=emb[f][e]
    d4 acc = {0.0, 0.0, 0.0, 0.0};
    for (int f = fbeg; f < fend; f += 4) {
      acc = __builtin_amdgcn_mfma_f64_16x16x4f64((double)Ap[0], (double)Bp[0], acc, 0, 0, 0);
      Ap += (size_t)4*S_;
      Bp += (size_t)4*E_;
    }
    const int rb = D2 ? (l >> 4) : ((l >> 4) << 2);   // first row of this lane's 4 D values
    const int rs = D2 ? 4 : 1;                        // row stride between regs
    double* op = part + (size_t)c*BSE_ + (size_t)(b*S_ + s0 + rb)*E_ + e0 + (l & 15);
    op[0]               = acc[0];
    op[(size_t)rs*E_]   = acc[1];
    op[(size_t)2*rs*E_] = acc[2];
    op[(size_t)3*rs*E_] = acc[3];
  } else {
    // VALU fallback (correct for any MFMA layout surprise)
    const int m = l & 15, kq = l >> 4;
    double a0 = 0.0, a1 = 0.0, a2 = 0.0, a3 = 0.0;
    const float* ipb = inputs + (size_t)(b*F_ + fbeg)*S_ + s0 + 4*kq;
    const float* epb = embedding + (size_t)fbeg*E_ + e0 + m;
    for (int f = fbeg; f < fend; f++) {
      double e = (double)epb[0];
      a0 += (double)ipb[0] * e;
      a1 += (double)ipb[1] * e;
      a2 += (double)ipb[2] * e;
      a3 += (double)ipb[3] * e;
      ipb += S_; epb += E_;
    }
    double* op = part + (size_t)c*BSE_ + (size_t)(b*S_ + s0 + 4*kq)*E_ + e0 + m;
    op[0] = a0; op[E_] = a1; op[2*E_] = a2; op[3*E_] = a3;
  }
}

// sum 8 partials + tanh -> emb64 (emb64 aliases part[6]; read-all-then-write-own is safe)
__global__ __launch_bounds__(256) void reduce_tanh_kernel(float* __restrict__ outbase) {
  const size_t j = (size_t)blockIdx.x*256 + threadIdx.x;   // 0..BSE_-1
  const double* part = (const double*)outbase;
  double s = 0.0;
#pragma unroll
  for (int c = 0; c < NCHUNK_; c++) s += part[(size_t)c*BSE_ + j];
  double* emb64 = (double*)(outbase + 3*(size_t)BSS_);
  emb64[j] = tanh(s);
}

// ---------------- stage B: logits = emb @ W[i] + b; probs = clip(sigmoid) ----------------
__global__ __launch_bounds__(256) void logits_kernel(const double* __restrict__ emb64,
                                                     const float* __restrict__ W,
                                                     const float* __restrict__ bias,
                                                     double* __restrict__ p64,
                                                     float* __restrict__ p32) {
  const int i  = blockIdx.x >> 3;
  const int o0 = (blockIdx.x & 7) << 6;
  const int t  = threadIdx.x;
  const int o  = o0 + (t & 63);
  const int bg = t >> 6;                  // wave id: batches bg and bg+4
  __shared__ double eL[8][128];
#pragma unroll
  for (int k = 0; k < 4; k++) {
    int q = t + k*256;
    eL[q >> 7][q & 127] = emb64[(size_t)((q >> 7)*S_ + i)*E_ + (q & 127)];
  }
  __syncthreads();
  double a0 = 0.0, a1 = 0.0;
  const float* Wp = W + (size_t)i*H_*S_ + o;
  for (int h = 0; h < H_; h++) {
    double w = (double)Wp[(size_t)h*S_];
    a0 += eL[bg][h]     * w;
    a1 += eL[bg + 4][h] * w;
  }
  double bd = (double)bias[i*S_ + o];
  double q0 = 1.0 / (1.0 + exp(-(a0 + bd)));
  double q1 = 1.0 / (1.0 + exp(-(a1 + bd)));
  q0 = fmin(fmax(q0, 1e-4), 1.0 - 1e-4);
  q1 = fmin(fmax(q1, 1e-4), 1.0 - 1e-4);
  size_t i0 = (size_t)(bg*S_ + i)*S_ + o;
  size_t i1 = (size_t)((bg + 4)*S_ + i)*S_ + o;
  p64[i0] = q0; p64[i1] = q1;
  p32[i0] = (float)q0; p32[i1] = (float)q1;
}

// ---------------- stage C: per-(step,b): bernoulli bits & top-8 keep, bit-packed ----------------
__global__ __launch_bounds__(64) void samppre_kernel(const double* __restrict__ p64,
                                                     float* __restrict__ outbase) {
  const int i = blockIdx.x >> 3;
  const int b = blockIdx.x & 7;
  const int l = threadIdx.x;
  ull* samp_pre = (ull*)(outbase + 3*(size_t)BSS_ + (size_t)b*S2_);  // 32KB/b, dead emb zone
  uint32_t k0, k1;
  splitkey(i, k0, k1);
  double pv[8]; bool sb[8]; bool usedk[8]; bool keep[8];
#pragma unroll
  for (int w = 0; w < 8; w++) {
    int c = (w << 6) + l;
    uint32_t m = (uint32_t)(b*S_ + c);      // flat index into (B,S)
    uint32_t bits = randbits32(k0, k1, m);
    float uf = __uint_as_float((bits >> 9) | 0x3f800000u) - 1.0f;
    double p = p64[(size_t)(b*S_ + i)*S_ + c];
    pv[w] = p;
    sb[w] = ((double)uf < p) && (c != i);
    usedk[w] = false; keep[w] = false;
  }
  for (int r = 0; r < TOPK_; r++) {
    double bp = -1.0; int bc = 0x7fffffff;
#pragma unroll
    for (int w = 0; w < 8; w++) {
      int c = (w << 6) + l;
      if (!usedk[w] && (pv[w] > bp || (pv[w] == bp && c < bc))) { bp = pv[w]; bc = c; }
    }
#pragma unroll
    for (int d = 1; d < 64; d <<= 1) {
      double op = __shfl_xor(bp, d);
      int    oc = __shfl_xor(bc, d);
      if (op > bp || (op == bp && oc < bc)) { bp = op; bc = oc; }
    }
    if ((bc & 63) == l) { usedk[bc >> 6] = true; keep[bc >> 6] = true; }
  }
#pragma unroll
  for (int w = 0; w < 8; w++) {
    ull word = __ballot((int)(sb[w] && keep[w]));
    if (l == 0) samp_pre[i*8 + w] = word;
  }
}

// ---------------- stage D: 2 batch-scans per block (16 waves), 8 waves per batch ----------------
// Block handles batches 2*blockIdx+{0,1}. Within a half: wave v owns bank v (nodes a=64v+l);
// Dw[w] = bits c in [64w,64w+64) of "a is ancestor of c". samp_pre staged in LDS;
// row(idx) via per-half 128B dbuf LDS; one shared barrier per step covers both chains,
// doubling per-SIMD issue (4 waves/SIMD) to cover the ~800cy/step stall window.
__global__ __launch_bounds__(1024, 1) void scan_kernel(float* __restrict__ outbase) {
  const int half = threadIdx.x >> 9;            // 0 or 1
  const int b  = blockIdx.x*2 + half;
  const int ht = threadIdx.x & 511;
  const int wv = ht >> 6;                       // owned bank
  const int l  = ht & 63;
  const ull* __restrict__ samp_pre = (const ull*)(outbase + 3*(size_t)BSS_ + (size_t)b*S2_);
  ull* sampPack = (ull*)(outbase + (size_t)BSS_) + (size_t)b*8192;   // region 1 (p64 dead): 32KB
  ull* Dpack    = sampPack + 4096;                                   // +32KB

  __shared__ ull spreL[2][4096];     // staged samp_pre per half (2x32KB)
  __shared__ ull rowbuf[2][2][8];    // [half][parity][word]
  for (int q = ht; q < 4096; q += 512) spreL[half][q] = samp_pre[q];
  if (ht < 16) rowbuf[half][ht >> 3][ht & 7] = 0ULL;
  ull Dw[8];
#pragma unroll
  for (int w = 0; w < 8; w++) Dw[w] = 0ULL;
  __syncthreads();

#pragma unroll
  for (int iw = 0; iw < 8; iw++) {            // compile-time bank of idx
    for (int ib = 0; ib < 64; ib++) {         // idx = 64*iw + ib
      const int idx  = (iw << 6) + ib;
      const int nidx = (idx + 1) & (S_ - 1);
      const int niw  = nidx >> 6, nib = nidx & 63;
      // row = D(idx) from previous step's owner; spre words: direct LDS reads
      ull row[8];
#pragma unroll
      for (int w = 0; w < 8; w++) row[w] = rowbuf[half][idx & 1][w];
      const ull row_v = rowbuf[half][idx & 1][wv];
      const ull pre_v = spreL[half][(idx << 3) + wv];
      ull sw[8];
#pragma unroll
      for (int w = 0; w < 8; w++) sw[w] = spreL[half][(idx << 3) + w] & ~row[w];
      const ull swv = pre_v & ~row_v;
      // t: "a=64wv+l is ancestor of idx, or of any selected c" (skip empty samp words)
      const ull ibit = 1ULL << ib;
      ull t = Dw[iw] & ibit;
#pragma unroll
      for (int w = 0; w < 8; w++) {
        if (sw[w] != 0ULL) t |= Dw[w] & sw[w];
      }
      // col for own bank = ballot | samp bits
      const ull col = __ballot((int)(t != 0ULL)) | swv;
      // propagate: for a in col: D(a) |= row | {idx}; skip empty row words (uniform-execz)
      if (col != 0ULL) {
        const ull m = 0ULL - ((col >> l) & 1ULL);
        Dw[iw] |= (row[iw] | ibit) & m;
#pragma unroll
        for (int w = 0; w < 8; w++) {
          if (w != iw && row[w] != 0ULL) Dw[w] |= row[w] & m;
        }
      }
      // owner of next step publishes row(nidx) early (critical cross-wave datum)
      if (wv == niw && l == nib) {
#pragma unroll
        for (int w = 0; w < 8; w++) rowbuf[half][nidx & 1][w] = Dw[w];
      }
      // emit packed samp (wave 0 of each half, lanes 0..7) — off the critical path
      if (wv == 0) {
        ull myw = sw[0];
#pragma unroll
        for (int w = 1; w < 8; w++) myw = (l == w) ? sw[w] : myw;
        if (l < 8) sampPack[(idx << 3) + l] = myw;
      }
      __syncthreads();
    }
  }
  // dump packed descendant sets: Dpack[((v*8+w)*64) + l] = Dw[w] (coalesced per wave)
#pragma unroll
  for (int w = 0; w < 8; w++)
    Dpack[(((wv << 3) + w) << 6) + l] = Dw[w];
}

// ---------------- stage E: expand packed bits -> float outputs (fully parallel) ----------------
__global__ __launch_bounds__(256) void expand_kernel(float* __restrict__ outbase) {
  const ull* pack = (const ull*)(outbase + (size_t)BSS_);
  unsigned int tid = blockIdx.x*256 + threadIdx.x;      // 0..524287
  const unsigned int half = 1u << 18;                   // 262144 groups of 8 floats each
  if (tid < half) {
    // out_idx[b][r][c] = bit c of sampPack[b][r*8 + c>>6]
    unsigned int t = tid;
    int b = t >> 15, tin = t & 32767, r = tin >> 6, cg = tin & 63;
    ull word = pack[(size_t)b*8192 + (r << 3) + (cg >> 3)];
    int sh = (cg & 7) << 3;
    float* dst = outbase + 2*(size_t)BSS_ + ((size_t)b << 18) + (r << 9) + (cg << 3);
    float4 v0 = make_float4((float)((word >> (sh+0)) & 1ULL), (float)((word >> (sh+1)) & 1ULL),
                            (float)((word >> (sh+2)) & 1ULL), (float)((word >> (sh+3)) & 1ULL));
    float4 v1 = make_float4((float)((word >> (sh+4)) & 1ULL), (float)((word >> (sh+5)) & 1ULL),
                            (float)((word >> (sh+6)) & 1ULL), (float)((word >> (sh+7)) & 1ULL));
    ((float4*)dst)[0] = v0; ((float4*)dst)[1] = v1;
  } else {
    // out_mask[b][a][c] = bit (a&63) of Dpack[b][((a>>6)*8 + (c>>6))*64 + (a&63)]
    unsigned int t = tid - half;
    int b = t >> 15, tin = t & 32767, a = tin >> 6, cg = tin & 63;
    const ull* Dp = pack + (size_t)b*8192 + 4096;
    ull word = Dp[((((a >> 6) << 3) + (cg >> 3)) << 6) + (a & 63)];
    int sh = (cg & 7) << 3;
    float* dst = outbase + 3*(size_t)BSS_ + ((size_t)b << 18) + (a << 9) + (cg << 3);
    float4 v0 = make_float4((float)((word >> (sh+0)) & 1ULL), (float)((word >> (sh+1)) & 1ULL),
                            (float)((word >> (sh+2)) & 1ULL), (float)((word >> (sh+3)) & 1ULL));
    float4 v1 = make_float4((float)((word >> (sh+4)) & 1ULL), (float)((word >> (sh+5)) & 1ULL),
                            (float)((word >> (sh+6)) & 1ULL), (float)((word >> (sh+7)) & 1ULL));
    ((float4*)dst)[0] = v0; ((float4*)dst)[1] = v1;
  }
}

extern "C" void kernel_launch(void* const* d_in, const int* in_sizes, int n_in,
                              void* d_out, int out_size, void* d_ws, size_t ws_size,
                              hipStream_t stream) {
  const float* inputs    = (const float*)d_in[0];
  const float* embedding = (const float*)d_in[1];
  const float* W         = (const float*)d_in[2];
  const float* bias      = (const float*)d_in[3];
  // d_in[4] = offset_prob: unused by the reference.
  float* out = (float*)d_out;
  // scratch timeline (all in d_out, no d_ws dependence):
  //  [t0] embed partials: 8 x 4MB f64 = ALL 32MB of d_out
  //  [t1] reduce_tanh: emb64 (4MB) at region-3 head (aliases part[6]; read-then-write safe)
  //  [t2] logits: reads emb64; writes p64 (regions 1-2) + p32 (region 0) — partials dead
  //  [t3] samppre: reads p64; writes samp_pre (32KB per b, region-3 b-zones) — emb64 dead
  //  [t4] scan: reads samp_pre; writes packed samp+D (64KB per b) into region 1 — p64 dead
  //  [t5] expand: reads region-1 packs; writes out_idx (region 2) + out_mask (region 3)
  //  [t6] memset region 1 (prev_probs_2 = 0)
  double* part  = (double*)out;
  double* emb64 = (double*)(out + 3*(size_t)BSS_);
  double* p64   = (double*)(out + (size_t)BSS_);

  embed_kernel      <<<4096, 256,  0, stream>>>(inputs, embedding, part);
  reduce_tanh_kernel<<<2048, 256,  0, stream>>>(out);
  logits_kernel     <<<4096, 256,  0, stream>>>(emb64, W, bias, p64, out);
  samppre_kernel    <<<4096, 64,   0, stream>>>(p64, out);
  scan_kernel       <<<4,    1024, 0, stream>>>(out);
  expand_kernel     <<<2048, 256,  0, stream>>>(out);
  hipMemsetAsync(out + (size_t)BSS_, 0, (size_t)BSS_ * sizeof(float), stream);  // prev_probs_2 = 0
}

// Round 17
// 494.201 us; speedup vs baseline: 1.3449x; 1.3449x over previous
//
#include <hip/hip_runtime.h>
#include <stdint.h>

// PointerNet: B=8, F=4000, S=512, E=H=128, TOPK=8, USE_MASK=1, EPS=1e-4
#define S_    512
#define B_    8
#define F_    4000
#define E_    128
#define H_    128
#define TOPK_ 8
#define S2_   (S_*S_)        // 262144
#define BSS_  (B_*S2_)       // 2097152
#define BSE_  (B_*S_*E_)     // 524288 (f64 elements per embed partial = 4MB)
#define NCHUNK_ 8
typedef unsigned long long ull;
typedef __attribute__((ext_vector_type(4))) double d4;

// ---------------- threefry2x32 (exact JAX semantics) ----------------
__device__ __forceinline__ void tf2x32(uint32_t k0, uint32_t k1, uint32_t& x0, uint32_t& x1) {
  uint32_t k2 = k0 ^ k1 ^ 0x1BD11BDAu;
  x0 += k0; x1 += k1;
#define TFR(r) { x0 += x1; x1 = (x1 << (r)) | (x1 >> (32 - (r))); x1 ^= x0; }
  TFR(13) TFR(15) TFR(26) TFR(6)
  x0 += k1; x1 += k2 + 1u;
  TFR(17) TFR(29) TFR(16) TFR(24)
  x0 += k2; x1 += k0 + 2u;
  TFR(13) TFR(15) TFR(26) TFR(6)
  x0 += k0; x1 += k1 + 3u;
  TFR(17) TFR(29) TFR(16) TFR(24)
  x0 += k1; x1 += k2 + 4u;
  TFR(13) TFR(15) TFR(26) TFR(6)
  x0 += k2; x1 += k0 + 5u;
#undef TFR
}

// jax_threefry_partitionable=True (modern JAX default)
__device__ __forceinline__ void splitkey(int i, uint32_t& k0, uint32_t& k1) {
  uint32_t x0 = 0u, x1 = (uint32_t)i;
  tf2x32(0u, 42u, x0, x1);   // key(42) = (0, 42)
  k0 = x0; k1 = x1;
}
__device__ __forceinline__ uint32_t randbits32(uint32_t k0, uint32_t k1, uint32_t m) {
  uint32_t x0 = 0u, x1 = m;
  tf2x32(k0, k1, x0, x1);
  return x0 ^ x1;
}

// ---------------- stage A: split-K partial f64 GEMM via f64 MFMA, self-calibrating ----------------
// Wave computes a 16(s) x 16(e) tile of part[c][b] over K = F-chunk, 4 k per MFMA.
// Fragment lane-mapping PROBED at runtime (2 MFMAs); unknown signature -> VALU fallback.
__global__ __launch_bounds__(256) void embed_kernel(const float* __restrict__ inputs,
                                                    const float* __restrict__ embedding,
                                                    double* __restrict__ part) {
  const int wid = blockIdx.x*4 + (threadIdx.x >> 6);
  const int c  = wid >> 11;                  // F-chunk 0..7
  const int b  = (wid >> 8) & 7;
  const int s0 = ((wid >> 3) & 31) << 4;
  const int e0 = (wid & 7) << 4;
  const int fbeg = c << 9;
  const int fend = (fbeg + 512 < F_) ? fbeg + 512 : F_;   // 512,...,512,416 (all %4==0)
  const int l  = threadIdx.x & 63;

  // ---- probe the HW fragment mapping (wave-uniform signatures) ----
  d4 z = {0.0, 0.0, 0.0, 0.0};
  double lv = (double)l;
  d4 p1 = __builtin_amdgcn_mfma_f64_16x16x4f64(lv, 1.0, z, 0, 0, 0);  // D[m][n]=sum_k A[m][k]
  d4 p2 = __builtin_amdgcn_mfma_f64_16x16x4f64(1.0, lv, z, 0, 0, 0);  // D[m][n]=sum_k B[k][n]
  const int sig1 = __builtin_amdgcn_readlane((int)p1[1], 0);  // 100/112/22/70 -> (A,D) combo
  const int sig2 = __builtin_amdgcn_readlane((int)p2[0], 1);  // 100/22       -> B combo
  const bool known = (sig1 == 100 || sig1 == 112 || sig1 == 22 || sig1 == 70) &&
                     (sig2 == 100 || sig2 == 22);

  if (known) {
    const bool A2 = (sig1 == 22) || (sig1 == 70);
    const bool D2 = (sig1 == 112) || (sig1 == 70);
    const bool B2 = (sig2 == 22);
    const int mA = A2 ? (l >> 2) : (l & 15);
    const int kA = A2 ? (l & 3)  : (l >> 4);
    const int nB = B2 ? (l >> 2) : (l & 15);
    const int kB = B2 ? (l & 3)  : (l >> 4);
    const float* Ap = inputs    + (size_t)(b*F_ + fbeg + kA)*S_ + s0 + mA;  // A[m][k]=in[f][s]
    const float* Bp = embedding + (size_t)(fbeg + kB)*E_ + e0 + nB;         // B[k][n]=emb[f][e]
    d4 acc = {0.0, 0.0, 0.0, 0.0};
    for (int f = fbeg; f < fend; f += 4) {
      acc = __builtin_amdgcn_mfma_f64_16x16x4f64((double)Ap[0], (double)Bp[0], acc, 0, 0, 0);
      Ap += (size_t)4*S_;
      Bp += (size_t)4*E_;
    }
    const int rb = D2 ? (l >> 4) : ((l >> 4) << 2);   // first row of this lane's 4 D values
    const int rs = D2 ? 4 : 1;                        // row stride between regs
    double* op = part + (size_t)c*BSE_ + (size_t)(b*S_ + s0 + rb)*E_ + e0 + (l & 15);
    op[0]               = acc[0];
    op[(size_t)rs*E_]   = acc[1];
    op[(size_t)2*rs*E_] = acc[2];
    op[(size_t)3*rs*E_] = acc[3];
  } else {
    // VALU fallback (correct for any MFMA layout surprise)
    const int m = l & 15, kq = l >> 4;
    double a0 = 0.0, a1 = 0.0, a2 = 0.0, a3 = 0.0;
    const float* ipb = inputs + (size_t)(b*F_ + fbeg)*S_ + s0 + 4*kq;
    const float* epb = embedding + (size_t)fbeg*E_ + e0 + m;
    for (int f = fbeg; f < fend; f++) {
      double e = (double)epb[0];
      a0 += (double)ipb[0] * e;
      a1 += (double)ipb[1] * e;
      a2 += (double)ipb[2] * e;
      a3 += (double)ipb[3] * e;
      ipb += S_; epb += E_;
    }
    double* op = part + (size_t)c*BSE_ + (size_t)(b*S_ + s0 + 4*kq)*E_ + e0 + m;
    op[0] = a0; op[E_] = a1; op[2*E_] = a2; op[3*E_] = a3;
  }
}

// sum 8 partials + tanh -> emb64 (emb64 aliases part[6]; read-all-then-write-own is safe)
__global__ __launch_bounds__(256) void reduce_tanh_kernel(float* __restrict__ outbase) {
  const size_t j = (size_t)blockIdx.x*256 + threadIdx.x;   // 0..BSE_-1
  const double* part = (const double*)outbase;
  double s = 0.0;
#pragma unroll
  for (int c = 0; c < NCHUNK_; c++) s += part[(size_t)c*BSE_ + j];
  double* emb64 = (double*)(outbase + 3*(size_t)BSS_);
  emb64[j] = tanh(s);
}

// ---------------- stage B: logits = emb @ W[i] + b; probs = clip(sigmoid) ----------------
// 128-thread blocks (2 waves); wave bg computes batches 4bg..4bg+3 for 64 o-columns:
// each W load now feeds 4 FMAs (was 2) -> half the load-issue per block.
__global__ __launch_bounds__(128) void logits_kernel(const double* __restrict__ emb64,
                                                     const float* __restrict__ W,
                                                     const float* __restrict__ bias,
                                                     double* __restrict__ p64,
                                                     float* __restrict__ p32) {
  const int i  = blockIdx.x >> 3;
  const int o0 = (blockIdx.x & 7) << 6;
  const int t  = threadIdx.x;
  const int o  = o0 + (t & 63);
  const int bg = t >> 6;                  // wave id: batches 4bg..4bg+3
  __shared__ double eL[8][128];
#pragma unroll
  for (int k = 0; k < 8; k++) {           // batch k, element t: coalesced 128-wide rows
    eL[k][t] = emb64[(size_t)(k*S_ + i)*E_ + t];
  }
  __syncthreads();
  double a0 = 0.0, a1 = 0.0, a2 = 0.0, a3 = 0.0;
  const float* Wp = W + (size_t)i*H_*S_ + o;
  const int b0 = bg << 2;
  for (int h = 0; h < H_; h++) {
    double w = (double)Wp[(size_t)h*S_];
    a0 += eL[b0    ][h] * w;
    a1 += eL[b0 + 1][h] * w;
    a2 += eL[b0 + 2][h] * w;
    a3 += eL[b0 + 3][h] * w;
  }
  double bd = (double)bias[i*S_ + o];
  double q0 = 1.0 / (1.0 + exp(-(a0 + bd)));
  double q1 = 1.0 / (1.0 + exp(-(a1 + bd)));
  double q2 = 1.0 / (1.0 + exp(-(a2 + bd)));
  double q3 = 1.0 / (1.0 + exp(-(a3 + bd)));
  q0 = fmin(fmax(q0, 1e-4), 1.0 - 1e-4);
  q1 = fmin(fmax(q1, 1e-4), 1.0 - 1e-4);
  q2 = fmin(fmax(q2, 1e-4), 1.0 - 1e-4);
  q3 = fmin(fmax(q3, 1e-4), 1.0 - 1e-4);
  size_t i0 = (size_t)((b0    )*S_ + i)*S_ + o;
  size_t i1 = (size_t)((b0 + 1)*S_ + i)*S_ + o;
  size_t i2 = (size_t)((b0 + 2)*S_ + i)*S_ + o;
  size_t i3 = (size_t)((b0 + 3)*S_ + i)*S_ + o;
  p64[i0] = q0; p64[i1] = q1; p64[i2] = q2; p64[i3] = q3;
  p32[i0] = (float)q0; p32[i1] = (float)q1; p32[i2] = (float)q2; p32[i3] = (float)q3;
}

// ---------------- stage C: per-(step,b): bernoulli bits & top-8 keep, bit-packed ----------------
__global__ __launch_bounds__(64) void samppre_kernel(const double* __restrict__ p64,
                                                     float* __restrict__ outbase) {
  const int i = blockIdx.x >> 3;
  const int b = blockIdx.x & 7;
  const int l = threadIdx.x;
  ull* samp_pre = (ull*)(outbase + 3*(size_t)BSS_ + (size_t)b*S2_);  // 32KB/b, dead emb zone
  uint32_t k0, k1;
  splitkey(i, k0, k1);
  double pv[8]; bool sb[8]; bool usedk[8]; bool keep[8];
#pragma unroll
  for (int w = 0; w < 8; w++) {
    int c = (w << 6) + l;
    uint32_t m = (uint32_t)(b*S_ + c);      // flat index into (B,S)
    uint32_t bits = randbits32(k0, k1, m);
    float uf = __uint_as_float((bits >> 9) | 0x3f800000u) - 1.0f;
    double p = p64[(size_t)(b*S_ + i)*S_ + c];
    pv[w] = p;
    sb[w] = ((double)uf < p) && (c != i);
    usedk[w] = false; keep[w] = false;
  }
  for (int r = 0; r < TOPK_; r++) {
    double bp = -1.0; int bc = 0x7fffffff;
#pragma unroll
    for (int w = 0; w < 8; w++) {
      int c = (w << 6) + l;
      if (!usedk[w] && (pv[w] > bp || (pv[w] == bp && c < bc))) { bp = pv[w]; bc = c; }
    }
#pragma unroll
    for (int d = 1; d < 64; d <<= 1) {
      double op = __shfl_xor(bp, d);
      int    oc = __shfl_xor(bc, d);
      if (op > bp || (op == bp && oc < bc)) { bp = op; bc = oc; }
    }
    if ((bc & 63) == l) { usedk[bc >> 6] = true; keep[bc >> 6] = true; }
  }
#pragma unroll
  for (int w = 0; w < 8; w++) {
    ull word = __ballot((int)(sb[w] && keep[w]));
    if (l == 0) samp_pre[i*8 + w] = word;
  }
}

// ---------------- stage D: per-batch scan, 8 waves splitting the 8 D-banks (R15 form) ----------------
// Block b = batch b. Wave v owns bank v: nodes a = 64v + l; Dw[w] = bits c in [64w,64w+64)
// of "a is ancestor of c". samp_pre staged in LDS; direct per-step LDS reads;
// cross-wave traffic = row(idx) via 128B double-buffered LDS; one barrier per step.
__global__ __launch_bounds__(512, 1) void scan_kernel(float* __restrict__ outbase) {
  const int b  = blockIdx.x;
  const int wv = threadIdx.x >> 6;   // owned bank
  const int l  = threadIdx.x & 63;
  const ull* __restrict__ samp_pre = (const ull*)(outbase + 3*(size_t)BSS_ + (size_t)b*S2_);
  ull* sampPack = (ull*)(outbase + (size_t)BSS_) + (size_t)b*8192;   // region 1 (p64 dead): 32KB
  ull* Dpack    = sampPack + 4096;                                   // +32KB

  __shared__ ull spreL[4096];        // staged samp_pre (32KB)
  __shared__ ull rowbuf[2][8];       // double-buffered row(idx) broadcast
  for (int q = threadIdx.x; q < 4096; q += 512) spreL[q] = samp_pre[q];
  if (threadIdx.x < 16) ((ull*)rowbuf)[threadIdx.x] = 0ULL;
  ull Dw[8];
#pragma unroll
  for (int w = 0; w < 8; w++) Dw[w] = 0ULL;
  __syncthreads();

#pragma unroll
  for (int iw = 0; iw < 8; iw++) {            // compile-time bank of idx
    for (int ib = 0; ib < 64; ib++) {         // idx = 64*iw + ib
      const int idx  = (iw << 6) + ib;
      const int nidx = (idx + 1) & (S_ - 1);
      const int niw  = nidx >> 6, nib = nidx & 63;
      // row = D(idx) from previous step's owner; spre words: direct LDS reads
      ull row[8];
#pragma unroll
      for (int w = 0; w < 8; w++) row[w] = rowbuf[idx & 1][w];
      const ull row_v = rowbuf[idx & 1][wv];
      const ull pre_v = spreL[(idx << 3) + wv];
      ull sw[8];
#pragma unroll
      for (int w = 0; w < 8; w++) sw[w] = spreL[(idx << 3) + w] & ~row[w];
      const ull swv = pre_v & ~row_v;
      // t: "a=64wv+l is ancestor of idx, or of any selected c" (skip empty samp words)
      const ull ibit = 1ULL << ib;
      ull t = Dw[iw] & ibit;
#pragma unroll
      for (int w = 0; w < 8; w++) {
        if (sw[w] != 0ULL) t |= Dw[w] & sw[w];
      }
      // col for own bank = ballot | samp bits
      const ull col = __ballot((int)(t != 0ULL)) | swv;
      // propagate: for a in col: D(a) |= row | {idx}; skip empty row words (uniform-execz)
      if (col != 0ULL) {
        const ull m = 0ULL - ((col >> l) & 1ULL);
        Dw[iw] |= (row[iw] | ibit) & m;
#pragma unroll
        for (int w = 0; w < 8; w++) {
          if (w != iw && row[w] != 0ULL) Dw[w] |= row[w] & m;
        }
      }
      // owner of next step publishes row(nidx) early (critical cross-wave datum)
      if (wv == niw && l == nib) {
#pragma unroll
        for (int w = 0; w < 8; w++) rowbuf[nidx & 1][w] = Dw[w];
      }
      // emit packed samp (wave 0, lanes 0..7) — off the critical path
      if (wv == 0) {
        ull myw = sw[0];
#pragma unroll
        for (int w = 1; w < 8; w++) myw = (l == w) ? sw[w] : myw;
        if (l < 8) sampPack[(idx << 3) + l] = myw;
      }
      __syncthreads();
    }
  }
  // dump packed descendant sets: Dpack[((v*8+w)*64) + l] = Dw[w] (coalesced per wave)
#pragma unroll
  for (int w = 0; w < 8; w++)
    Dpack[(((wv << 3) + w) << 6) + l] = Dw[w];
}

// ---------------- stage E: expand packed bits -> float outputs (fully parallel) ----------------
__global__ __launch_bounds__(256) void expand_kernel(float* __restrict__ outbase) {
  const ull* pack = (const ull*)(outbase + (size_t)BSS_);
  unsigned int tid = blockIdx.x*256 + threadIdx.x;      // 0..524287
  const unsigned int half = 1u << 18;                   // 262144 groups of 8 floats each
  if (tid < half) {
    // out_idx[b][r][c] = bit c of sampPack[b][r*8 + c>>6]
    unsigned int t = tid;
    int b = t >> 15, tin = t & 32767, r = tin >> 6, cg = tin & 63;
    ull word = pack[(size_t)b*8192 + (r << 3) + (cg >> 3)];
    int sh = (cg & 7) << 3;
    float* dst = outbase + 2*(size_t)BSS_ + ((size_t)b << 18) + (r << 9) + (cg << 3);
    float4 v0 = make_float4((float)((word >> (sh+0)) & 1ULL), (float)((word >> (sh+1)) & 1ULL),
                            (float)((word >> (sh+2)) & 1ULL), (float)((word >> (sh+3)) & 1ULL));
    float4 v1 = make_float4((float)((word >> (sh+4)) & 1ULL), (float)((word >> (sh+5)) & 1ULL),
                            (float)((word >> (sh+6)) & 1ULL), (float)((word >> (sh+7)) & 1ULL));
    ((float4*)dst)[0] = v0; ((float4*)dst)[1] = v1;
  } else {
    // out_mask[b][a][c] = bit (a&63) of Dpack[b][((a>>6)*8 + (c>>6))*64 + (a&63)]
    unsigned int t = tid - half;
    int b = t >> 15, tin = t & 32767, a = tin >> 6, cg = tin & 63;
    const ull* Dp = pack + (size_t)b*8192 + 4096;
    ull word = Dp[((((a >> 6) << 3) + (cg >> 3)) << 6) + (a & 63)];
    int sh = (cg & 7) << 3;
    float* dst = outbase + 3*(size_t)BSS_ + ((size_t)b << 18) + (a << 9) + (cg << 3);
    float4 v0 = make_float4((float)((word >> (sh+0)) & 1ULL), (float)((word >> (sh+1)) & 1ULL),
                            (float)((word >> (sh+2)) & 1ULL), (float)((word >> (sh+3)) & 1ULL));
    float4 v1 = make_float4((float)((word >> (sh+4)) & 1ULL), (float)((word >> (sh+5)) & 1ULL),
                            (float)((word >> (sh+6)) & 1ULL), (float)((word >> (sh+7)) & 1ULL));
    ((float4*)dst)[0] = v0; ((float4*)dst)[1] = v1;
  }
}

extern "C" void kernel_launch(void* const* d_in, const int* in_sizes, int n_in,
                              void* d_out, int out_size, void* d_ws, size_t ws_size,
                              hipStream_t stream) {
  const float* inputs    = (const float*)d_in[0];
  const float* embedding = (const float*)d_in[1];
  const float* W         = (const float*)d_in[2];
  const float* bias      = (const float*)d_in[3];
  // d_in[4] = offset_prob: unused by the reference.
  float* out = (float*)d_out;
  // scratch timeline (all in d_out, no d_ws dependence):
  //  [t0] embed partials: 8 x 4MB f64 = ALL 32MB of d_out
  //  [t1] reduce_tanh: emb64 (4MB) at region-3 head (aliases part[6]; read-then-write safe)
  //  [t2] logits: reads emb64; writes p64 (regions 1-2) + p32 (region 0) — partials dead
  //  [t3] samppre: reads p64; writes samp_pre (32KB per b, region-3 b-zones) — emb64 dead
  //  [t4] scan: reads samp_pre; writes packed samp+D (64KB per b) into region 1 — p64 dead
  //  [t5] expand: reads region-1 packs; writes out_idx (region 2) + out_mask (region 3)
  //  [t6] memset region 1 (prev_probs_2 = 0)
  double* part  = (double*)out;
  double* emb64 = (double*)(out + 3*(size_t)BSS_);
  double* p64   = (double*)(out + (size_t)BSS_);

  embed_kernel      <<<4096, 256, 0, stream>>>(inputs, embedding, part);
  reduce_tanh_kernel<<<2048, 256, 0, stream>>>(out);
  logits_kernel     <<<4096, 128, 0, stream>>>(emb64, W, bias, p64, out);
  samppre_kernel    <<<4096, 64,  0, stream>>>(p64, out);
  scan_kernel       <<<8,    512, 0, stream>>>(out);
  expand_kernel     <<<2048, 256, 0, stream>>>(out);
  hipMemsetAsync(out + (size_t)BSS_, 0, (size_t)BSS_ * sizeof(float), stream);  // prev_probs_2 = 0
}